// Round 1
// baseline (868.918 us; speedup 1.0000x reference)
//
#include <hip/hip_runtime.h>

#define Bz   4
#define Nn   16384
#define Ss   4096
#define D1   128
#define D2   256
#define INCH 384
#define C0   256
#define C1   128
#define Mtot (Bz*Nn)   // 65536

typedef unsigned short u16;
struct __align__(8) us4 { u16 x, y, z, w; };

__device__ __forceinline__ float bf2f(u16 u) {
  union { unsigned u; float f; } x; x.u = ((unsigned)u) << 16; return x.f;
}
__device__ __forceinline__ u16 f2bf(float f) {
  union { float f; unsigned u; } x; x.f = f;
  unsigned r = x.u + 0x7fffu + ((x.u >> 16) & 1u);
  return (u16)(r >> 16);
}

// ---------------------------------------------------------------------------
// Kernel A: 3-NN + inverse-distance interpolation + concat -> Xb (bf16, [M][384])
// One block = 256 query points (one batch slice); xyz2 staged in LDS in 2 chunks.
// ---------------------------------------------------------------------------
__global__ __launch_bounds__(256) void knn_interp_kernel(
    const float* __restrict__ xyz1, const float* __restrict__ xyz2,
    const float* __restrict__ points1, const float* __restrict__ points2,
    u16* __restrict__ Xb)
{
  __shared__ float4 s_q[2048];
  __shared__ int    s_i[256][3];
  __shared__ float  s_w[256][3];
  const int t  = threadIdx.x;
  const int b  = blockIdx.x >> 6;          // 64 blocks per batch
  const int n0 = (blockIdx.x & 63) << 8;   // 256 points per block

  const float* xp = xyz1 + (size_t)(b*Nn + n0 + t)*3;
  const float px = xp[0], py = xp[1], pz = xp[2];
  const float n1 = px*px + py*py + pz*pz;
  float c0 = 3.4e38f, c1 = 3.4e38f, c2 = 3.4e38f;
  int j0 = 0, j1 = 0, j2 = 0;
  const float* x2 = xyz2 + (size_t)b*Ss*3;

  for (int s0 = 0; s0 < Ss; s0 += 2048) {
    __syncthreads();
    for (int i = t; i < 2048; i += 256) {
      const float* q = x2 + (size_t)(s0 + i)*3;
      float qx = q[0], qy = q[1], qz = q[2];
      s_q[i] = make_float4(qx, qy, qz, qx*qx + qy*qy + qz*qz);
    }
    __syncthreads();
    #pragma unroll 4
    for (int j = 0; j < 2048; ++j) {
      float4 q = s_q[j];
      float dot = fmaf(px, q.x, fmaf(py, q.y, pz*q.z));
      float d = fmaf(-2.f, dot, n1 + q.w);
      if (d < c2) {                      // strict '<' keeps earlier index on ties
        int s = s0 + j;
        if (d < c1) {
          c2 = c1; j2 = j1;
          if (d < c0) { c1 = c0; j1 = j0; c0 = d; j0 = s; }
          else        { c1 = d;  j1 = s; }
        } else { c2 = d; j2 = s; }
      }
    }
  }
  {
    float r0 = 1.f/(c0 + 1e-8f), r1 = 1.f/(c1 + 1e-8f), r2 = 1.f/(c2 + 1e-8f);
    float rs = 1.f/(r0 + r1 + r2);
    s_i[t][0] = j0; s_i[t][1] = j1; s_i[t][2] = j2;
    s_w[t][0] = r0*rs; s_w[t][1] = r1*rs; s_w[t][2] = r2*rs;
  }
  __syncthreads();

  // points1 -> Xb[:, 0:128] (coalesced, float4 -> 4x bf16)
  const float* p1 = points1 + (size_t)(b*Nn + n0)*D1;
  u16* xrow = Xb + (size_t)(b*Nn + n0)*INCH;
  for (int i = t; i < 256*(D1/4); i += 256) {
    int r  = i >> 5;
    int cq = (i & 31) << 2;
    float4 v = *(const float4*)(p1 + (size_t)r*D1 + cq);
    us4 o = { f2bf(v.x), f2bf(v.y), f2bf(v.z), f2bf(v.w) };
    *(us4*)(xrow + (size_t)r*INCH + cq) = o;
  }
  // interp -> Xb[:, 128:384]; 4 points at a time, 64 lanes cover 256 channels
  const float* p2 = points2 + (size_t)b*Ss*D2;
  const int sub = t >> 6;
  const int cg  = (t & 63) << 2;
  for (int i = 0; i < 64; ++i) {
    int p = (i << 2) + sub;
    int i0 = s_i[p][0], i1 = s_i[p][1], i2 = s_i[p][2];
    float w0 = s_w[p][0], w1 = s_w[p][1], w2 = s_w[p][2];
    float4 f0 = *(const float4*)(p2 + (size_t)i0*D2 + cg);
    float4 f1 = *(const float4*)(p2 + (size_t)i1*D2 + cg);
    float4 f2 = *(const float4*)(p2 + (size_t)i2*D2 + cg);
    float v0 = w0*f0.x + w1*f1.x + w2*f2.x;
    float v1 = w0*f0.y + w1*f1.y + w2*f2.y;
    float v2 = w0*f0.z + w1*f1.z + w2*f2.z;
    float v3 = w0*f0.w + w1*f1.w + w2*f2.w;
    us4 o = { f2bf(v0), f2bf(v1), f2bf(v2), f2bf(v3) };
    *(us4*)(xrow + (size_t)p*INCH + D1 + cg) = o;
  }
}

// ---------------------------------------------------------------------------
// Tiled GEMM: out[M][ldout] = X[M][K](bf16) * W[Nout][K]^T + bias
// BM=BN=64, BK=32, 256 threads, 4x4 microtile, fp32 accumulate.
// ---------------------------------------------------------------------------
template<int K, bool OUT_BF16>
__global__ __launch_bounds__(256) void gemm_kernel(
    const u16* __restrict__ X, const float* __restrict__ W,
    const float* __restrict__ bias, void* __restrict__ out, int ldout)
{
  __shared__ float Xs[32][68];
  __shared__ float Ws[32][68];
  const int t  = threadIdx.x;
  const int tx = t & 15, ty = t >> 4;
  const int n0 = blockIdx.x * 64;   // x = col tile: consecutive blocks share X panel
  const int m0 = blockIdx.y * 64;
  const int r  = t >> 2, q = t & 3;
  float acc[4][4] = {};
  const u16*   xp = X + (size_t)(m0 + r)*K + q*8;
  const float* wp = W + (size_t)(n0 + r)*K + q*8;

  for (int k0 = 0; k0 < K; k0 += 32) {
    uint4  xv  = *(const uint4*)(xp + k0);
    float4 wv0 = *(const float4*)(wp + k0);
    float4 wv1 = *(const float4*)(wp + k0 + 4);
    __syncthreads();
    const int kq = q*8;
    Xs[kq+0][r] = bf2f((u16)(xv.x & 0xffff));
    Xs[kq+1][r] = bf2f((u16)(xv.x >> 16));
    Xs[kq+2][r] = bf2f((u16)(xv.y & 0xffff));
    Xs[kq+3][r] = bf2f((u16)(xv.y >> 16));
    Xs[kq+4][r] = bf2f((u16)(xv.z & 0xffff));
    Xs[kq+5][r] = bf2f((u16)(xv.z >> 16));
    Xs[kq+6][r] = bf2f((u16)(xv.w & 0xffff));
    Xs[kq+7][r] = bf2f((u16)(xv.w >> 16));
    Ws[kq+0][r] = wv0.x; Ws[kq+1][r] = wv0.y; Ws[kq+2][r] = wv0.z; Ws[kq+3][r] = wv0.w;
    Ws[kq+4][r] = wv1.x; Ws[kq+5][r] = wv1.y; Ws[kq+6][r] = wv1.z; Ws[kq+7][r] = wv1.w;
    __syncthreads();
    #pragma unroll
    for (int kk = 0; kk < 32; ++kk) {
      float4 a  = *(const float4*)&Xs[kk][ty*4];
      float4 bv = *(const float4*)&Ws[kk][tx*4];
      acc[0][0] = fmaf(a.x, bv.x, acc[0][0]);
      acc[0][1] = fmaf(a.x, bv.y, acc[0][1]);
      acc[0][2] = fmaf(a.x, bv.z, acc[0][2]);
      acc[0][3] = fmaf(a.x, bv.w, acc[0][3]);
      acc[1][0] = fmaf(a.y, bv.x, acc[1][0]);
      acc[1][1] = fmaf(a.y, bv.y, acc[1][1]);
      acc[1][2] = fmaf(a.y, bv.z, acc[1][2]);
      acc[1][3] = fmaf(a.y, bv.w, acc[1][3]);
      acc[2][0] = fmaf(a.z, bv.x, acc[2][0]);
      acc[2][1] = fmaf(a.z, bv.y, acc[2][1]);
      acc[2][2] = fmaf(a.z, bv.z, acc[2][2]);
      acc[2][3] = fmaf(a.z, bv.w, acc[2][3]);
      acc[3][0] = fmaf(a.w, bv.x, acc[3][0]);
      acc[3][1] = fmaf(a.w, bv.y, acc[3][1]);
      acc[3][2] = fmaf(a.w, bv.z, acc[3][2]);
      acc[3][3] = fmaf(a.w, bv.w, acc[3][3]);
    }
  }

  const float4 bb = *(const float4*)(bias + n0 + tx*4);
  #pragma unroll
  for (int i = 0; i < 4; ++i) {
    size_t row = (size_t)m0 + ty*4 + i;
    float o0 = acc[i][0] + bb.x, o1 = acc[i][1] + bb.y;
    float o2 = acc[i][2] + bb.z, o3 = acc[i][3] + bb.w;
    if constexpr (OUT_BF16) {
      us4 o = { f2bf(o0), f2bf(o1), f2bf(o2), f2bf(o3) };
      *(us4*)((u16*)out + row*ldout + n0 + tx*4) = o;
    } else {
      float4 o = make_float4(o0, o1, o2, o3);
      *(float4*)((float*)out + row*ldout + n0 + tx*4) = o;
    }
  }
}

// ---------------------------------------------------------------------------
// Column stats (deterministic 2-stage): partial sums/sumsq per channel
// ---------------------------------------------------------------------------
__global__ __launch_bounds__(256) void stats_partial_bf16(
    const u16* __restrict__ Y, float* __restrict__ partial, int rows)
{
  const int C = blockDim.x;
  const int c = threadIdx.x;
  const u16* p = Y + (size_t)blockIdx.x*rows*C + c;
  float s = 0.f, sq = 0.f;
  #pragma unroll 4
  for (int r = 0; r < rows; ++r) {
    float v = bf2f(p[(size_t)r*C]);
    s += v; sq = fmaf(v, v, sq);
  }
  float* o = partial + (size_t)blockIdx.x*2*C;
  o[c] = s; o[C + c] = sq;
}

__global__ __launch_bounds__(256) void stats_partial_f32(
    const float* __restrict__ Y, float* __restrict__ partial, int rows)
{
  const int C = blockDim.x;
  const int c = threadIdx.x;
  const float* p = Y + (size_t)blockIdx.x*rows*C + c;
  float s = 0.f, sq = 0.f;
  #pragma unroll 4
  for (int r = 0; r < rows; ++r) {
    float v = p[(size_t)r*C];
    s += v; sq = fmaf(v, v, sq);
  }
  float* o = partial + (size_t)blockIdx.x*2*C;
  o[c] = s; o[C + c] = sq;
}

__global__ void stats_finish(const float* __restrict__ partial, int nblk,
    const float* __restrict__ gamma, const float* __restrict__ beta,
    float* __restrict__ AB)
{
  const int C = blockDim.x;
  const int c = threadIdx.x;
  float s = 0.f, sq = 0.f;
  for (int i = 0; i < nblk; ++i) {
    s  += partial[(size_t)i*2*C + c];
    sq += partial[(size_t)i*2*C + C + c];
  }
  const float inv = 1.0f / (float)Mtot;
  float mean = s * inv;
  float var  = fmaf(-mean, mean, sq * inv);
  float a = rsqrtf(var + 1e-5f) * gamma[c];
  AB[c]     = a;
  AB[C + c] = fmaf(-mean, a, beta[c]);
}

// ---------------------------------------------------------------------------
// Normalize + ReLU, in place
// ---------------------------------------------------------------------------
__global__ __launch_bounds__(256) void norm_relu_bf16(u16* __restrict__ Y,
                                                      const float* __restrict__ AB)
{
  size_t g = (size_t)blockIdx.x * 256 + threadIdx.x;  // group of 8 bf16
  u16* p = Y + g*8;
  int c0 = (int)((g*8) & (C0-1));
  uint4 v = *(const uint4*)p;
  float4 a0 = *(const float4*)(AB + c0);
  float4 a1 = *(const float4*)(AB + c0 + 4);
  float4 b0 = *(const float4*)(AB + C0 + c0);
  float4 b1 = *(const float4*)(AB + C0 + c0 + 4);
  float f0 = fmaxf(0.f, fmaf(bf2f((u16)(v.x & 0xffff)), a0.x, b0.x));
  float f1 = fmaxf(0.f, fmaf(bf2f((u16)(v.x >> 16)),    a0.y, b0.y));
  float f2 = fmaxf(0.f, fmaf(bf2f((u16)(v.y & 0xffff)), a0.z, b0.z));
  float f3 = fmaxf(0.f, fmaf(bf2f((u16)(v.y >> 16)),    a0.w, b0.w));
  float f4 = fmaxf(0.f, fmaf(bf2f((u16)(v.z & 0xffff)), a1.x, b1.x));
  float f5 = fmaxf(0.f, fmaf(bf2f((u16)(v.z >> 16)),    a1.y, b1.y));
  float f6 = fmaxf(0.f, fmaf(bf2f((u16)(v.w & 0xffff)), a1.z, b1.z));
  float f7 = fmaxf(0.f, fmaf(bf2f((u16)(v.w >> 16)),    a1.w, b1.w));
  uint4 o;
  o.x = (unsigned)f2bf(f0) | ((unsigned)f2bf(f1) << 16);
  o.y = (unsigned)f2bf(f2) | ((unsigned)f2bf(f3) << 16);
  o.z = (unsigned)f2bf(f4) | ((unsigned)f2bf(f5) << 16);
  o.w = (unsigned)f2bf(f6) | ((unsigned)f2bf(f7) << 16);
  *(uint4*)p = o;
}

__global__ __launch_bounds__(256) void norm_relu_f32(float* __restrict__ Y,
                                                     const float* __restrict__ AB)
{
  size_t g = (size_t)blockIdx.x * 256 + threadIdx.x;  // group of 4 f32
  float* p = Y + g*4;
  int c0 = (int)((g*4) & (C1-1));
  float4 v = *(const float4*)p;
  float4 a = *(const float4*)(AB + c0);
  float4 b = *(const float4*)(AB + C1 + c0);
  v.x = fmaxf(0.f, fmaf(v.x, a.x, b.x));
  v.y = fmaxf(0.f, fmaf(v.y, a.y, b.y));
  v.z = fmaxf(0.f, fmaf(v.z, a.z, b.z));
  v.w = fmaxf(0.f, fmaf(v.w, a.w, b.w));
  *(float4*)p = v;
}

// ---------------------------------------------------------------------------
extern "C" void kernel_launch(void* const* d_in, const int* in_sizes, int n_in,
                              void* d_out, int out_size, void* d_ws, size_t ws_size,
                              hipStream_t stream) {
  const float* xyz1    = (const float*)d_in[0];
  const float* xyz2    = (const float*)d_in[1];
  const float* points1 = (const float*)d_in[2];
  const float* points2 = (const float*)d_in[3];
  const float* w0  = (const float*)d_in[4];
  const float* b0  = (const float*)d_in[5];
  const float* g0  = (const float*)d_in[6];
  const float* be0 = (const float*)d_in[7];
  const float* w1  = (const float*)d_in[8];
  const float* b1  = (const float*)d_in[9];
  const float* g1  = (const float*)d_in[10];
  const float* be1 = (const float*)d_in[11];
  float* out = (float*)d_out;
  char* ws = (char*)d_ws;

  const size_t XB_OFF   = 0;                                  // 50,331,648 B
  const size_t Y1_OFF   = (size_t)Mtot*INCH*2;                // + 33,554,432 B
  const size_t PART_OFF = Y1_OFF + (size_t)Mtot*C0*2;         // + 1,048,576 B
  const size_t AB0_OFF  = PART_OFF + (size_t)512*2*256*4;
  const size_t AB1_OFF  = AB0_OFF + 2048;

  u16*   Xb      = (u16*)(ws + XB_OFF);
  u16*   Y1      = (u16*)(ws + Y1_OFF);
  float* partial = (float*)(ws + PART_OFF);
  float* AB0     = (float*)(ws + AB0_OFF);
  float* AB1     = (float*)(ws + AB1_OFF);

  // 1) KNN + interpolation + concat (bf16)
  knn_interp_kernel<<<dim3(Bz*(Nn/256)), dim3(256), 0, stream>>>(
      xyz1, xyz2, points1, points2, Xb);
  // 2) GEMM1: [M,384]x[384,256] -> raw Y1 (bf16)
  gemm_kernel<INCH, true><<<dim3(C0/64, Mtot/64), dim3(256), 0, stream>>>(
      Xb, w0, b0, (void*)Y1, C0);
  // 3) BN0 stats
  stats_partial_bf16<<<dim3(512), dim3(C0), 0, stream>>>(Y1, partial, Mtot/512);
  stats_finish<<<dim3(1), dim3(C0), 0, stream>>>(partial, 512, g0, be0, AB0);
  // 4) normalize+relu Y1 in place
  norm_relu_bf16<<<dim3((size_t)Mtot*C0/8/256), dim3(256), 0, stream>>>(Y1, AB0);
  // 5) GEMM2: [M,256]x[256,128] -> raw Y2 (f32) in d_out
  gemm_kernel<C0, false><<<dim3(C1/64, Mtot/64), dim3(256), 0, stream>>>(
      Y1, w1, b1, (void*)out, C1);
  // 6) BN1 stats
  stats_partial_f32<<<dim3(512), dim3(C1), 0, stream>>>(out, partial, Mtot/512);
  stats_finish<<<dim3(1), dim3(C1), 0, stream>>>(partial, 512, g1, be1, AB1);
  // 7) normalize+relu d_out in place
  norm_relu_f32<<<dim3((size_t)Mtot*C1/4/256), dim3(256), 0, stream>>>(out, AB1);
}

// Round 2
// 390.690 us; speedup vs baseline: 2.2241x; 2.2241x over previous
//
#include <hip/hip_runtime.h>

#define Bz   4
#define Nn   16384
#define Ss   4096
#define D1   128
#define D2   256
#define INCH 384
#define C0   256
#define C1   128
#define Mtot 65536
#define NCHUNK 16
#define SC    256   // sources per chunk

typedef unsigned short u16;
typedef __attribute__((ext_vector_type(4))) float f32x4;
typedef __attribute__((ext_vector_type(8))) short bf16x8;
struct __align__(8) us4 { u16 x, y, z, w; };

__device__ __forceinline__ float bf2f(u16 u) {
  union { unsigned u; float f; } x; x.u = ((unsigned)u) << 16; return x.f;
}
__device__ __forceinline__ u16 f2bf(float f) {
  union { float f; unsigned u; } x; x.f = f;
  unsigned r = x.u + 0x7fffu + ((x.u >> 16) & 1u);
  return (u16)(r >> 16);
}
__device__ __forceinline__ void gload16(const void* g, void* l) {
  __builtin_amdgcn_global_load_lds(
      (const __attribute__((address_space(1))) unsigned*)g,
      (__attribute__((address_space(3))) unsigned*)l, 16, 0, 0);
}

// ---------------------------------------------------------------------------
// K1: partial top-3 per (query, source-chunk). Branchless insert, Q=4/thread.
// grid = 64 query-blocks (1024 q each) x 16 chunks (256 src each) = 1024 blocks
// key = |x2|^2 - 2*dot  (monotone in squared distance; n1 added at merge)
// ---------------------------------------------------------------------------
__global__ __launch_bounds__(256) void knn_partial(
    const float* __restrict__ xyz1, const float* __restrict__ xyz2,
    float* __restrict__ pkey, int* __restrict__ pidx)
{
  __shared__ float4 s_q[SC];
  const int t     = threadIdx.x;
  const int chunk = blockIdx.x & (NCHUNK - 1);
  const int qb    = blockIdx.x >> 4;         // 0..63
  const int b     = qb >> 4;                 // batch (16 q-blocks per batch)
  const int qbase = qb << 10;                // 1024 queries per q-block

  {
    const float* src = xyz2 + ((size_t)b * Ss + chunk * SC + t) * 3;
    float x = src[0], y = src[1], z = src[2];
    s_q[t] = make_float4(x, y, z, x*x + y*y + z*z);
  }
  float qx[4], qy[4], qz[4];
  float c0[4], c1[4], c2[4];
  int   j0[4], j1[4], j2[4];
  #pragma unroll
  for (int i = 0; i < 4; ++i) {
    const float* p = xyz1 + ((size_t)qbase + i * 256 + t) * 3;
    qx[i] = p[0]; qy[i] = p[1]; qz[i] = p[2];
    c0[i] = 3.4e38f; c1[i] = 3.4e38f; c2[i] = 3.4e38f;
    j0[i] = 0; j1[i] = 0; j2[i] = 0;
  }
  __syncthreads();

  const int sbase = chunk * SC;
  #pragma unroll 4
  for (int j = 0; j < SC; ++j) {
    float4 q = s_q[j];
    int s = sbase + j;
    #pragma unroll
    for (int i = 0; i < 4; ++i) {
      float dot = fmaf(qx[i], q.x, fmaf(qy[i], q.y, qz[i] * q.z));
      float key = fmaf(-2.f, dot, q.w);
      bool l0 = key < c0[i], l1 = key < c1[i], l2 = key < c2[i];
      c2[i] = l1 ? c1[i] : (l2 ? key : c2[i]);
      j2[i] = l1 ? j1[i] : (l2 ? s   : j2[i]);
      c1[i] = l0 ? c0[i] : (l1 ? key : c1[i]);
      j1[i] = l0 ? j0[i] : (l1 ? s   : j1[i]);
      c0[i] = l0 ? key   : c0[i];
      j0[i] = l0 ? s     : j0[i];
    }
  }
  #pragma unroll
  for (int i = 0; i < 4; ++i) {
    size_t q = (size_t)qbase + i * 256 + t;
    size_t o = ((size_t)chunk * Mtot + q) * 3;
    pkey[o] = c0[i]; pkey[o+1] = c1[i]; pkey[o+2] = c2[i];
    pidx[o] = j0[i]; pidx[o+1] = j1[i]; pidx[o+2] = j2[i];
  }
}

// ---------------------------------------------------------------------------
// K2: merge 16 partials -> top-3, weights, gather points2, concat -> Xb bf16
// 1024 blocks x 256 threads; 64 queries per block.
// ---------------------------------------------------------------------------
__global__ __launch_bounds__(256) void knn_merge_interp(
    const float* __restrict__ xyz1,
    const float* __restrict__ points1, const float* __restrict__ points2,
    const float* __restrict__ pkey, const int* __restrict__ pidx,
    u16* __restrict__ Xb)
{
  __shared__ int   s_i[64][3];
  __shared__ float s_w[64][3];
  const int t = threadIdx.x;
  const size_t qbase = (size_t)blockIdx.x * 64;
  const int b = (int)(qbase >> 14);

  if (t < 64) {
    size_t q = qbase + t;
    float c0 = 3.4e38f, c1 = 3.4e38f, c2 = 3.4e38f;
    int   j0 = 0, j1 = 0, j2 = 0;
    for (int c = 0; c < NCHUNK; ++c) {
      size_t o = ((size_t)c * Mtot + q) * 3;
      #pragma unroll
      for (int r = 0; r < 3; ++r) {
        float key = pkey[o + r]; int s = pidx[o + r];
        bool l0 = key < c0, l1 = key < c1, l2 = key < c2;
        c2 = l1 ? c1 : (l2 ? key : c2); j2 = l1 ? j1 : (l2 ? s : j2);
        c1 = l0 ? c0 : (l1 ? key : c1); j1 = l0 ? j0 : (l1 ? s : j1);
        c0 = l0 ? key : c0;             j0 = l0 ? s : j0;
      }
    }
    const float* p = xyz1 + q * 3;
    float n1 = p[0]*p[0] + p[1]*p[1] + p[2]*p[2];
    float r0 = 1.f / (c0 + n1 + 1e-8f);
    float r1 = 1.f / (c1 + n1 + 1e-8f);
    float r2 = 1.f / (c2 + n1 + 1e-8f);
    float rs = 1.f / (r0 + r1 + r2);
    s_i[t][0] = j0; s_i[t][1] = j1; s_i[t][2] = j2;
    s_w[t][0] = r0 * rs; s_w[t][1] = r1 * rs; s_w[t][2] = r2 * rs;
  }
  __syncthreads();

  // points1 -> Xb[:, 0:128]
  const float* p1 = points1 + qbase * D1;
  u16* xr = Xb + qbase * INCH;
  #pragma unroll
  for (int k = 0; k < 8; ++k) {
    int i = k * 256 + t;             // 2048 float4 chunks
    int r = i >> 5, c4 = (i & 31) << 2;
    float4 v = *(const float4*)(p1 + (size_t)r * D1 + c4);
    us4 o = { f2bf(v.x), f2bf(v.y), f2bf(v.z), f2bf(v.w) };
    *(us4*)(xr + (size_t)r * INCH + c4) = o;
  }
  // interp -> Xb[:, 128:384]
  const float* p2 = points2 + (size_t)b * Ss * D2;
  const int sub = t >> 6, cg = (t & 63) << 2;
  #pragma unroll 2
  for (int pass = 0; pass < 16; ++pass) {
    int p = pass * 4 + sub;
    int i0 = s_i[p][0], i1 = s_i[p][1], i2 = s_i[p][2];
    float w0 = s_w[p][0], w1 = s_w[p][1], w2 = s_w[p][2];
    float4 f0 = *(const float4*)(p2 + (size_t)i0 * D2 + cg);
    float4 f1 = *(const float4*)(p2 + (size_t)i1 * D2 + cg);
    float4 f2 = *(const float4*)(p2 + (size_t)i2 * D2 + cg);
    float v0 = w0*f0.x + w1*f1.x + w2*f2.x;
    float v1 = w0*f0.y + w1*f1.y + w2*f2.y;
    float v2 = w0*f0.z + w1*f1.z + w2*f2.z;
    float v3 = w0*f0.w + w1*f1.w + w2*f2.w;
    us4 o = { f2bf(v0), f2bf(v1), f2bf(v2), f2bf(v3) };
    *(us4*)(xr + (size_t)p * INCH + D1 + cg) = o;
  }
}

// ---------------------------------------------------------------------------
// fp32 -> bf16 weight conversion
// ---------------------------------------------------------------------------
__global__ __launch_bounds__(256) void cvt_bf16_kernel(
    const float* __restrict__ s, u16* __restrict__ d, int n4)
{
  int i = blockIdx.x * 256 + threadIdx.x;
  if (i < n4) {
    float4 v = *(const float4*)(s + (size_t)i * 4);
    us4 o = { f2bf(v.x), f2bf(v.y), f2bf(v.z), f2bf(v.w) };
    *(us4*)(d + (size_t)i * 4) = o;
  }
}

// ---------------------------------------------------------------------------
// MFMA GEMM: out[M][NOUT] = X[M][K](bf16) * Wb[NOUT][K](bf16)^T + bias
// 128x128 tile, BK=64, 4 waves (2x2 of 64x64), 16x16x32 bf16 MFMA.
// LDS XOR-swizzle (byte ^ (row&7)<<4) via inverse-swizzled global source
// (global_load_lds writes linearly) + swizzled ds_read_b128.
// ---------------------------------------------------------------------------
template<int K, int NOUT, bool OUT_BF16>
__global__ __launch_bounds__(256) void gemm_mfma(
    const u16* __restrict__ X, const u16* __restrict__ Wb,
    const float* __restrict__ bias, void* __restrict__ out)
{
  __shared__ u16 ldsA[128 * 64];
  __shared__ u16 ldsB[128 * 64];
  const int t = threadIdx.x;
  const int w = t >> 6, lane = t & 63;
  const int m0 = blockIdx.y * 128, n0 = blockIdx.x * 128;
  const int wm = (w >> 1) * 64, wn = (w & 1) * 64;

  f32x4 acc[4][4];
  #pragma unroll
  for (int mi = 0; mi < 4; ++mi)
    #pragma unroll
    for (int ni = 0; ni < 4; ++ni)
      acc[mi][ni] = (f32x4){0.f, 0.f, 0.f, 0.f};

  // staging sources: chunk ci covers LDS bytes [(ci*256+t)*16, +16)
  const char* aS[4]; const char* bS[4];
  #pragma unroll
  for (int ci = 0; ci < 4; ++ci) {
    int d  = (ci * 256 + t) * 16;
    int r  = d >> 7;                 // row 0..127
    int cb = d & 127;                // byte-in-row
    int cbs = cb ^ ((r & 7) << 4);   // inverse swizzle on SOURCE
    aS[ci] = (const char*)(X  + (size_t)(m0 + r) * K) + cbs;
    bS[ci] = (const char*)(Wb + (size_t)(n0 + r) * K) + cbs;
  }

  for (int kt = 0; kt < K / 64; ++kt) {
    __syncthreads();                 // previous tile consumed
    #pragma unroll
    for (int ci = 0; ci < 4; ++ci) {
      gload16(aS[ci] + kt * 128, (char*)ldsA + (ci * 256 + w * 64) * 16);
      gload16(bS[ci] + kt * 128, (char*)ldsB + (ci * 256 + w * 64) * 16);
    }
    __syncthreads();                 // compiler drains vmcnt before barrier
    #pragma unroll
    for (int ks = 0; ks < 2; ++ks) {
      bf16x8 a[4], bfr[4];
      const int ka = ks * 64 + ((lane >> 4) << 4);
      #pragma unroll
      for (int x = 0; x < 4; ++x) {
        int ra = wm + x * 16 + (lane & 15);
        a[x]   = *(const bf16x8*)((const char*)ldsA + ra * 128 + (ka ^ ((ra & 7) << 4)));
        int rb = wn + x * 16 + (lane & 15);
        bfr[x] = *(const bf16x8*)((const char*)ldsB + rb * 128 + (ka ^ ((rb & 7) << 4)));
      }
      #pragma unroll
      for (int mi = 0; mi < 4; ++mi)
        #pragma unroll
        for (int ni = 0; ni < 4; ++ni)
          acc[mi][ni] = __builtin_amdgcn_mfma_f32_16x16x32_bf16(
              a[mi], bfr[ni], acc[mi][ni], 0, 0, 0);
    }
  }

  // epilogue: C/D layout col=lane&15, row=(lane>>4)*4+reg (m89-verified)
  const int col = lane & 15;
  const int rg  = (lane >> 4) << 2;
  #pragma unroll
  for (int ni = 0; ni < 4; ++ni) {
    int c = n0 + wn + ni * 16 + col;
    float bb = bias[c];
    #pragma unroll
    for (int mi = 0; mi < 4; ++mi) {
      int rbase = m0 + wm + mi * 16 + rg;
      #pragma unroll
      for (int rr = 0; rr < 4; ++rr) {
        float v = acc[mi][ni][rr] + bb;
        if constexpr (OUT_BF16)
          ((u16*)out)[(size_t)(rbase + rr) * NOUT + c] = f2bf(v);
        else
          ((float*)out)[(size_t)(rbase + rr) * NOUT + c] = v;
      }
    }
  }
}

// ---------------------------------------------------------------------------
// BN stats (deterministic 2-stage) + fold into per-channel (a,b)
// ---------------------------------------------------------------------------
__global__ __launch_bounds__(256) void stats_partial_bf16(
    const u16* __restrict__ Y, float* __restrict__ partial, int rows)
{
  const int C = blockDim.x;
  const int c = threadIdx.x;
  const u16* p = Y + (size_t)blockIdx.x * rows * C + c;
  float s = 0.f, sq = 0.f;
  #pragma unroll 4
  for (int r = 0; r < rows; ++r) {
    float v = bf2f(p[(size_t)r * C]);
    s += v; sq = fmaf(v, v, sq);
  }
  float* o = partial + (size_t)blockIdx.x * 2 * C;
  o[c] = s; o[C + c] = sq;
}

__global__ __launch_bounds__(256) void stats_partial_f32(
    const float* __restrict__ Y, float* __restrict__ partial, int rows)
{
  const int C = blockDim.x;
  const int c = threadIdx.x;
  const float* p = Y + (size_t)blockIdx.x * rows * C + c;
  float s = 0.f, sq = 0.f;
  #pragma unroll 4
  for (int r = 0; r < rows; ++r) {
    float v = p[(size_t)r * C];
    s += v; sq = fmaf(v, v, sq);
  }
  float* o = partial + (size_t)blockIdx.x * 2 * C;
  o[c] = s; o[C + c] = sq;
}

__global__ void stats_finish(const float* __restrict__ partial, int nblk,
    const float* __restrict__ gamma, const float* __restrict__ beta,
    float* __restrict__ AB)
{
  const int C = blockDim.x;
  const int c = threadIdx.x;
  float s = 0.f, sq = 0.f;
  for (int i = 0; i < nblk; ++i) {
    s  += partial[(size_t)i * 2 * C + c];
    sq += partial[(size_t)i * 2 * C + C + c];
  }
  const float inv = 1.0f / (float)Mtot;
  float mean = s * inv;
  float var  = fmaf(-mean, mean, sq * inv);
  float a = rsqrtf(var + 1e-5f) * gamma[c];
  AB[c]     = a;
  AB[C + c] = fmaf(-mean, a, beta[c]);
}

__global__ __launch_bounds__(256) void norm_relu_bf16(u16* __restrict__ Y,
                                                      const float* __restrict__ AB)
{
  size_t g = (size_t)blockIdx.x * 256 + threadIdx.x;  // 8 bf16 per thread
  u16* p = Y + g * 8;
  int c0 = (int)((g * 8) & (C0 - 1));
  uint4 v = *(const uint4*)p;
  float4 a0 = *(const float4*)(AB + c0);
  float4 a1 = *(const float4*)(AB + c0 + 4);
  float4 b0 = *(const float4*)(AB + C0 + c0);
  float4 b1 = *(const float4*)(AB + C0 + c0 + 4);
  float f0 = fmaxf(0.f, fmaf(bf2f((u16)(v.x & 0xffff)), a0.x, b0.x));
  float f1 = fmaxf(0.f, fmaf(bf2f((u16)(v.x >> 16)),    a0.y, b0.y));
  float f2 = fmaxf(0.f, fmaf(bf2f((u16)(v.y & 0xffff)), a0.z, b0.z));
  float f3 = fmaxf(0.f, fmaf(bf2f((u16)(v.y >> 16)),    a0.w, b0.w));
  float f4 = fmaxf(0.f, fmaf(bf2f((u16)(v.z & 0xffff)), a1.x, b1.x));
  float f5 = fmaxf(0.f, fmaf(bf2f((u16)(v.z >> 16)),    a1.y, b1.y));
  float f6 = fmaxf(0.f, fmaf(bf2f((u16)(v.w & 0xffff)), a1.z, b1.z));
  float f7 = fmaxf(0.f, fmaf(bf2f((u16)(v.w >> 16)),    a1.w, b1.w));
  uint4 o;
  o.x = (unsigned)f2bf(f0) | ((unsigned)f2bf(f1) << 16);
  o.y = (unsigned)f2bf(f2) | ((unsigned)f2bf(f3) << 16);
  o.z = (unsigned)f2bf(f4) | ((unsigned)f2bf(f5) << 16);
  o.w = (unsigned)f2bf(f6) | ((unsigned)f2bf(f7) << 16);
  *(uint4*)p = o;
}

__global__ __launch_bounds__(256) void norm_relu_f32(float* __restrict__ Y,
                                                     const float* __restrict__ AB)
{
  size_t g = (size_t)blockIdx.x * 256 + threadIdx.x;  // 4 f32 per thread
  float* p = Y + g * 4;
  int c0 = (int)((g * 4) & (C1 - 1));
  float4 v = *(const float4*)p;
  float4 a = *(const float4*)(AB + c0);
  float4 b = *(const float4*)(AB + C1 + c0);
  v.x = fmaxf(0.f, fmaf(v.x, a.x, b.x));
  v.y = fmaxf(0.f, fmaf(v.y, a.y, b.y));
  v.z = fmaxf(0.f, fmaf(v.z, a.z, b.z));
  v.w = fmaxf(0.f, fmaf(v.w, a.w, b.w));
  *(float4*)p = v;
}

// ---------------------------------------------------------------------------
extern "C" void kernel_launch(void* const* d_in, const int* in_sizes, int n_in,
                              void* d_out, int out_size, void* d_ws, size_t ws_size,
                              hipStream_t stream) {
  const float* xyz1    = (const float*)d_in[0];
  const float* xyz2    = (const float*)d_in[1];
  const float* points1 = (const float*)d_in[2];
  const float* points2 = (const float*)d_in[3];
  const float* w0  = (const float*)d_in[4];
  const float* b0  = (const float*)d_in[5];
  const float* g0  = (const float*)d_in[6];
  const float* be0 = (const float*)d_in[7];
  const float* w1  = (const float*)d_in[8];
  const float* b1  = (const float*)d_in[9];
  const float* g1  = (const float*)d_in[10];
  const float* be1 = (const float*)d_in[11];
  float* out = (float*)d_out;
  char* ws = (char*)d_ws;

  // layout (<= round-1 footprint):
  const size_t XB_OFF   = 0;                              // 50,331,648
  const size_t Y1_OFF   = (size_t)Mtot * INCH * 2;        // 33,554,432 (Y1)
  // K1 partials overlay Y1 region (dead before GEMM1 writes Y1):
  const size_t PKEY_OFF = Y1_OFF;                         // 12,582,912
  const size_t PIDX_OFF = Y1_OFF + (size_t)NCHUNK * Mtot * 3 * 4;
  const size_t PART_OFF = Y1_OFF + (size_t)Mtot * C0 * 2; // 524,288 (256 blk)
  const size_t AB0_OFF  = PART_OFF + (size_t)256 * 2 * 256 * 4;
  const size_t AB1_OFF  = AB0_OFF + 2048;
  const size_t WB0_OFF  = AB1_OFF + 2048;                 // 196,608
  const size_t WB1_OFF  = WB0_OFF + (size_t)C0 * INCH * 2;// 65,536

  u16*   Xb      = (u16*)(ws + XB_OFF);
  u16*   Y1      = (u16*)(ws + Y1_OFF);
  float* pkey    = (float*)(ws + PKEY_OFF);
  int*   pidx    = (int*)(ws + PIDX_OFF);
  float* partial = (float*)(ws + PART_OFF);
  float* AB0     = (float*)(ws + AB0_OFF);
  float* AB1     = (float*)(ws + AB1_OFF);
  u16*   Wb0     = (u16*)(ws + WB0_OFF);
  u16*   Wb1     = (u16*)(ws + WB1_OFF);

  // 0) weights -> bf16
  cvt_bf16_kernel<<<dim3(96), dim3(256), 0, stream>>>(w0, Wb0, C0 * INCH / 4);
  cvt_bf16_kernel<<<dim3(32), dim3(256), 0, stream>>>(w1, Wb1, C1 * C0 / 4);
  // 1) KNN partial top-3
  knn_partial<<<dim3(64 * NCHUNK), dim3(256), 0, stream>>>(xyz1, xyz2, pkey, pidx);
  // 2) merge + interpolate + concat -> Xb
  knn_merge_interp<<<dim3(Mtot / 64), dim3(256), 0, stream>>>(
      xyz1, points1, points2, pkey, pidx, Xb);
  // 3) GEMM1 (MFMA): [M,384]x[384,256]^T -> Y1 bf16
  gemm_mfma<INCH, C0, true><<<dim3(C0 / 128, Mtot / 128), dim3(256), 0, stream>>>(
      Xb, Wb0, b0, (void*)Y1);
  // 4) BN0 stats + fold
  stats_partial_bf16<<<dim3(256), dim3(C0), 0, stream>>>(Y1, partial, Mtot / 256);
  stats_finish<<<dim3(1), dim3(C0), 0, stream>>>(partial, 256, g0, be0, AB0);
  // 5) normalize + relu Y1 in place
  norm_relu_bf16<<<dim3(Mtot * C0 / 8 / 256), dim3(256), 0, stream>>>(Y1, AB0);
  // 6) GEMM2 (MFMA): [M,256]x[256,128]^T -> d_out f32
  gemm_mfma<C0, C1, false><<<dim3(C1 / 128, Mtot / 128), dim3(256), 0, stream>>>(
      Y1, Wb1, b1, (void*)out);
  // 7) BN1 stats + fold
  stats_partial_f32<<<dim3(256), dim3(C1), 0, stream>>>(out, partial, Mtot / 256);
  stats_finish<<<dim3(1), dim3(C1), 0, stream>>>(partial, 256, g1, be1, AB1);
  // 8) normalize + relu d_out in place
  norm_relu_f32<<<dim3(Mtot * C1 / 4 / 256), dim3(256), 0, stream>>>(out, AB1);
}